// Round 3
// baseline (74.114 us; speedup 1.0000x reference)
//
#include <hip/hip_runtime.h>

// Grouped conv: x (1,48,56,56) f32, w (24,96,7) f32, groups=2.
// y[o,h,wo] = sum_{i<24,k<7} x[24g+i, h, wo+k-3] * w[i, o%96, k]   (pad 3 on W)
// out[o,h,:] = y[o, (h - shift) mod 56, :]   (jnp.roll along H)
//
// R3: occupancy experiment. 1 output channel per WAVE (was 2), grid doubled:
//   grid (96,14) x 128 threads = 2688 waves = 2.63 waves/SIMD (was 1.31).
//   Per wave: lane = (rl = lane>>4 row, c4 = lane&15 col-strip of 4).
//   Per input channel: 3 aligned float4 x-loads + 2 ds_read_b128 weight
//   broadcasts + 28 FMAs. Accumulation order per output unchanged.

#define Hh 56
#define Wd 56
#define HWsz (Hh * Wd)
#define CI 24
#define KW 7

__global__ __launch_bounds__(128) void conv7_roll_kernel(
    const float* __restrict__ x,
    const float* __restrict__ w,
    const int* __restrict__ shift_p,
    float* __restrict__ out)
{
    const int tid  = threadIdx.x;
    const int wid  = tid >> 6;          // 0..1 -> which oc of the pair
    const int lane = tid & 63;
    const int rl   = lane >> 4;         // 0..3 row within 4-row group
    const int c4r  = lane & 15;         // 0..15 (14,15 inactive)
    const int c4   = c4r < 13 ? c4r : 13;

    const int shift = shift_p[0];       // early scalar load

    const int obase = blockIdx.x * 2;   // 0..190, never straddles group (96 even)
    const int g     = obase / 96;
    const int ocb96 = obase - g * 96;

    // Stage weights for the block's 2 output channels: wl[oc_l][ci][8]
    __shared__ __align__(16) float wl[2 * CI * 8];
    for (int t = tid; t < 2 * CI * 8; t += 128) {
        const int oc_l = t / (CI * 8);
        const int rem  = t - oc_l * (CI * 8);
        const int ci   = rem >> 3;
        const int k    = rem & 7;
        wl[t] = (k < KW) ? w[ci * (96 * KW) + (ocb96 + oc_l) * KW + k] : 0.0f;
    }
    __syncthreads();

    const int h_out = blockIdx.y * 4 + rl;
    int hi = (h_out - shift) % Hh;
    if (hi < 0) hi += Hh;

    // All three load pointers stay inside row hi after clamping.
    const float* xp = x + g * (CI * HWsz) + hi * Wd + c4 * 4;
    const float* lp = xp + (c4 > 0  ? -4 : 0);
    const float* rp = xp + (c4 < 13 ?  4 : 0);
    const bool lz = (c4 == 0);
    const bool rz = (c4 >= 13);

    const float* wlw = &wl[wid * (CI * 8)];

    float a0[4] = {0.f, 0.f, 0.f, 0.f};

    #pragma unroll 4
    for (int ci = 0; ci < CI; ++ci) {
        float4 M = *(const float4*)(xp + ci * HWsz);
        float4 L = *(const float4*)(lp + ci * HWsz);
        float4 R = *(const float4*)(rp + ci * HWsz);
        if (lz) { L.x = 0.f; L.y = 0.f; L.z = 0.f; L.w = 0.f; }
        if (rz) { R.x = 0.f; R.y = 0.f; R.z = 0.f; R.w = 0.f; }
        // Window cols 4c4-4 .. 4c4+7; output col 4c4+j uses xv[1+j+k].
        float xv[12] = {L.x, L.y, L.z, L.w, M.x, M.y, M.z, M.w, R.x, R.y, R.z, R.w};

        float4 wa = *(const float4*)(wlw + ci * 8);
        float4 wb = *(const float4*)(wlw + ci * 8 + 4);
        float w0[7] = {wa.x, wa.y, wa.z, wa.w, wb.x, wb.y, wb.z};

        #pragma unroll
        for (int k = 0; k < KW; ++k) {
            #pragma unroll
            for (int j = 0; j < 4; ++j)
                a0[j] += xv[1 + j + k] * w0[k];
        }
    }

    if (c4r < 14) {
        const int o = obase + wid;
        float* op = out + o * HWsz + h_out * Wd + c4 * 4;
        *(float4*)op = make_float4(a0[0], a0[1], a0[2], a0[3]);
    }
}

extern "C" void kernel_launch(void* const* d_in, const int* in_sizes, int n_in,
                              void* d_out, int out_size, void* d_ws, size_t ws_size,
                              hipStream_t stream)
{
    const float* x     = (const float*)d_in[0];
    const float* w     = (const float*)d_in[1];
    const int*   shift = (const int*)d_in[2];
    float*       out   = (float*)d_out;

    dim3 grid(96, 14);   // 192/2 oc-pairs x 56/4 row-groups
    conv7_roll_kernel<<<grid, 128, 0, stream>>>(x, w, shift, out);
}

// Round 4
// 67.710 us; speedup vs baseline: 1.0946x; 1.0946x over previous
//
#include <hip/hip_runtime.h>

// Grouped conv: x (1,48,56,56) f32, w (24,96,7) f32, groups=2.
// y[o,h,wo] = sum_{i<24,k<7} x[24g+i, h, wo+k-3] * w[i, o%96, k]   (pad 3 on W)
// out[o,h,:] = y[o, (h - shift) mod 56, :]   (jnp.roll along H)
//
// R4: R2 geometry (best measured: grid 48x14, 128 thr, 2 oc/wave) + explicit
// depth-8 prefetch over input channels. x is cold every iteration (the 256 MB
// harness poison-fill evicts L2/L3), so ~900-cyc miss latency must be covered
// by in-flight loads: 24 float4 in flight covers it; unroll-4 (12) did not.

#define Hh 56
#define Wd 56
#define HWsz (Hh * Wd)
#define CI 24
#define KW 7
#define OCB 4   // output channels per block (2 per wave)
#define PF 8    // prefetch depth in input channels

__global__ __launch_bounds__(128) void conv7_roll_kernel(
    const float* __restrict__ x,
    const float* __restrict__ w,
    const int* __restrict__ shift_p,
    float* __restrict__ out)
{
    const int tid  = threadIdx.x;
    const int wid  = tid >> 6;          // 0..1  -> oc pair within block
    const int lane = tid & 63;
    const int rl   = lane >> 4;         // 0..3  row within 4-row group
    const int c4r  = lane & 15;         // 0..15 (14,15 inactive)
    const int c4   = c4r < 13 ? c4r : 13;

    const int shift = shift_p[0];

    const int obase = blockIdx.x * OCB; // 0,4,...,188 (never straddles group)
    const int g     = obase / 96;
    const int ocb96 = obase - g * 96;

    // Stage weights: wl[oc_l][ci][8] (k=7 is pad)
    __shared__ __align__(16) float wl[OCB * CI * 8];
    for (int t = tid; t < OCB * CI * 8; t += 128) {
        const int oc_l = t / (CI * 8);
        const int rem  = t - oc_l * (CI * 8);
        const int ci   = rem >> 3;
        const int k    = rem & 7;
        wl[t] = (k < KW) ? w[ci * (96 * KW) + (ocb96 + oc_l) * KW + k] : 0.0f;
    }
    __syncthreads();

    const int h_out = blockIdx.y * 4 + rl;
    int hi = (h_out - shift) % Hh;
    if (hi < 0) hi += Hh;

    // All loads stay inside row hi after clamping.
    const float* xg = x + g * (CI * HWsz) + hi * Wd + c4 * 4;
    const int dl = (c4 > 0  ? -4 : 0);
    const int dr = (c4 < 13 ?  4 : 0);
    const bool lz = (c4 == 0);
    const bool rz = (c4 >= 13);

    const float* wl0 = &wl[(wid * 2    ) * (CI * 8)];
    const float* wl1 = &wl[(wid * 2 + 1) * (CI * 8)];

    float a0[4] = {0.f, 0.f, 0.f, 0.f};
    float a1[4] = {0.f, 0.f, 0.f, 0.f};

    // Prologue: issue loads for ci = 0..PF-1 (24 float4 in flight).
    float4 Mb[PF], Lb[PF], Rb[PF];
    #pragma unroll
    for (int p = 0; p < PF; ++p) {
        const float* b = xg + p * HWsz;
        Mb[p] = *(const float4*)b;
        Lb[p] = *(const float4*)(b + dl);
        Rb[p] = *(const float4*)(b + dr);
    }

    #pragma unroll
    for (int ci = 0; ci < CI; ++ci) {
        const int s = ci % PF;          // compile-time after full unroll
        float4 M = Mb[s];
        float4 L = Lb[s];
        float4 R = Rb[s];
        if (ci + PF < CI) {             // re-issue this slot for ci+PF
            const float* b = xg + (ci + PF) * HWsz;
            Mb[s] = *(const float4*)b;
            Lb[s] = *(const float4*)(b + dl);
            Rb[s] = *(const float4*)(b + dr);
        }
        if (lz) { L.x = 0.f; L.y = 0.f; L.z = 0.f; L.w = 0.f; }
        if (rz) { R.x = 0.f; R.y = 0.f; R.z = 0.f; R.w = 0.f; }
        // Window cols 4c4-4 .. 4c4+7; output col 4c4+j uses xv[1+j+k].
        float xv[12] = {L.x, L.y, L.z, L.w, M.x, M.y, M.z, M.w, R.x, R.y, R.z, R.w};

        float4 wa = *(const float4*)(wl0 + ci * 8);
        float4 wb = *(const float4*)(wl0 + ci * 8 + 4);
        float4 wc = *(const float4*)(wl1 + ci * 8);
        float4 wd = *(const float4*)(wl1 + ci * 8 + 4);
        float w0[7] = {wa.x, wa.y, wa.z, wa.w, wb.x, wb.y, wb.z};
        float w1[7] = {wc.x, wc.y, wc.z, wc.w, wd.x, wd.y, wd.z};

        #pragma unroll
        for (int k = 0; k < KW; ++k) {
            #pragma unroll
            for (int j = 0; j < 4; ++j) {
                a0[j] += xv[1 + j + k] * w0[k];
                a1[j] += xv[1 + j + k] * w1[k];
            }
        }
    }

    if (c4r < 14) {
        const int o0 = obase + wid * 2;
        float* op0 = out + o0 * HWsz + h_out * Wd + c4 * 4;
        float* op1 = op0 + HWsz;
        *(float4*)op0 = make_float4(a0[0], a0[1], a0[2], a0[3]);
        *(float4*)op1 = make_float4(a1[0], a1[1], a1[2], a1[3]);
    }
}

extern "C" void kernel_launch(void* const* d_in, const int* in_sizes, int n_in,
                              void* d_out, int out_size, void* d_ws, size_t ws_size,
                              hipStream_t stream)
{
    const float* x     = (const float*)d_in[0];
    const float* w     = (const float*)d_in[1];
    const int*   shift = (const int*)d_in[2];
    float*       out   = (float*)d_out;

    dim3 grid(48, 14);   // 192/4 oc-groups x 56/4 row-groups
    conv7_roll_kernel<<<grid, 128, 0, stream>>>(x, w, shift, out);
}